// Round 11
// baseline (1118.211 us; speedup 1.0000x reference)
//
#include <hip/hip_runtime.h>
#include <math.h>

#define BN_EPS 1e-5f

typedef unsigned short ushort_t;
typedef unsigned int uint_t;
typedef _Float16 half_t;
typedef __attribute__((ext_vector_type(8))) short short8;     // 8 bf16 (4 VGPR)
typedef __attribute__((ext_vector_type(8))) _Float16 half8;   // 8 fp16 (4 VGPR)
typedef __attribute__((ext_vector_type(4))) unsigned uint4v;  // 4 dwords
typedef __attribute__((ext_vector_type(2))) unsigned uint2v;  // 2 dwords
typedef __attribute__((ext_vector_type(16))) float floatx16;  // MFMA 32x32 acc

// Split fp32 into bf16 hi (bit-truncate, exact) + bf16 lo (truncated remainder).
__device__ __forceinline__ void split_bf16(float v, ushort_t& h, ushort_t& l) {
    unsigned u = __float_as_uint(v);
    float fhi = __uint_as_float(u & 0xFFFF0000u);
    h = (ushort_t)(u >> 16);
    l = (ushort_t)(__float_as_uint(v - fhi) >> 16);
}

// Interleaved word: hi in high16, lo in low16.
__device__ __forceinline__ uint_t split_word(float v) {
    ushort_t h, l;
    split_bf16(v, h, l);
    return ((uint_t)h << 16) | (uint_t)l;
}

__device__ __forceinline__ float h2f_lo(uint_t u) {
    union { ushort_t s; half_t h; } cv; cv.s = (ushort_t)(u & 0xFFFFu);
    return (float)cv.h;
}
__device__ __forceinline__ float h2f_hi(uint_t u) {
    union { ushort_t s; half_t h; } cv; cv.s = (ushort_t)(u >> 16);
    return (float)cv.h;
}

// ---------------------------------------------------------------------------
// Weight prep (value convs): OIHW fp32 -> tiled [tap][o>>5][i>>3][o&31][i&7]
// bf16 hi/lo planes (split-bf16 3-MFMA path).
// ---------------------------------------------------------------------------
__global__ __launch_bounds__(256) void prep_w_kernel(
    const float* __restrict__ w, ushort_t* __restrict__ hi,
    ushort_t* __restrict__ lo, int O, int I)
{
    int idx = blockIdx.x * 256 + threadIdx.x;
    int n = 9 * O * I;
    if (idx >= n) return;
    int i = idx % I;
    int rest = idx / I;
    int o = rest % O;
    int t = rest / O;
    float v = w[((size_t)o * I + i) * 9 + t];
    size_t d = ((((size_t)t * (O / 32) + (o >> 5)) * (I / 8) + (i >> 3)) * 32
                + (o & 31)) * 8 + (i & 7);
    split_bf16(v, hi[d], lo[d]);
}

// ---------------------------------------------------------------------------
// Weight prep (deform offset convs): OIHW fp32 -> tiled fp16 single plane.
// ---------------------------------------------------------------------------
__global__ __launch_bounds__(256) void prep_wf16_kernel(
    const float* __restrict__ w, half_t* __restrict__ o, int O, int I)
{
    int idx = blockIdx.x * 256 + threadIdx.x;
    int n = 9 * O * I;
    if (idx >= n) return;
    int i = idx % I;
    int rest = idx / I;
    int oo = rest % O;
    int t = rest / O;
    float v = w[((size_t)oo * I + i) * 9 + t];
    size_t d = ((((size_t)t * (O / 32) + (oo >> 5)) * (I / 8) + (i >> 3)) * 32
                + (oo & 31)) * 8 + (i & 7);
    o[d] = (half_t)v;
}

// ---------------------------------------------------------------------------
// A prep, deform layers: NCHW fp32 + BN affine -> tiled fp16 plane (MFMA A)
// + LINEAR fp16 plane [b][c][H*W] (bilinear gather source).
// ---------------------------------------------------------------------------
__global__ __launch_bounds__(256) void pack_af16_kernel(
    const float* __restrict__ x, const float* __restrict__ aff,
    half_t* __restrict__ xt, half_t* __restrict__ xl,
    int C, int HW, int total)
{
    int idx = blockIdx.x * 256 + threadIdx.x;
    if (idx >= total) return;
    int p = idx % HW;
    int rest = idx / HW;
    int cg = rest % (C / 8);
    int b  = rest / (C / 8);
    const float* xp = x + ((size_t)b * C + cg * 8) * HW + p;
    half8 hv;
    #pragma unroll
    for (int j = 0; j < 8; j++) {
        int c = cg * 8 + j;
        float v = fmaf(xp[(size_t)j * HW], aff[2 * c], aff[2 * c + 1]);
        hv[j] = (half_t)v;
        xl[((size_t)b * C + c) * HW + p] = hv[j];
    }
    size_t base = (size_t)b * C * HW + ((size_t)(p >> 5) * (C / 8) + cg) * 256
                + (size_t)(p & 31) * 8;
    *(half8*)(xt + base) = hv;
}

// ---------------------------------------------------------------------------
__global__ void bn_finalize_kernel(
    const float* __restrict__ stats, const float* __restrict__ g,
    const float* __restrict__ be, float inv_cnt, float* __restrict__ aff, int C)
{
    int c = threadIdx.x;
    if (c < C) {
        float m  = stats[c] * inv_cnt;
        float vv = stats[C + c] * inv_cnt - m * m;
        float sc = g[c] / sqrtf(vv + BN_EPS);
        aff[2 * c]     = sc;
        aff[2 * c + 1] = be[c] - m * sc;
    }
}

// ---------------------------------------------------------------------------
// DEFORM kernel (fp16), round 26: EXACT r21/r7 structure (best verified
// 1045.6us). r25's bank-conflict re-pitch (PITCH 65 / stg 10) REDUCED
// conflicts 6.4M->2.4M but SLOWED deform22 211->230us — conflicts are off
// the critical path (epilogue is gather-latency bound). Reverted.
// ---------------------------------------------------------------------------
template<int W, int H, int CIN, int CO, int NT, int NZ>
__global__ __launch_bounds__(512, 4) void mfma_deform_g(
    const half_t* __restrict__ xt, const half_t* __restrict__ xl,
    const half_t* __restrict__ wf, uint_t* __restrict__ outp)
{
    constexpr int HWi = W * H;
    constexpr int KB  = CIN / 8;
    constexpr int TILES = HWi / 32;     // 32-pixel tiles per image
    constexpr int XTB = (TILES + 7) / 8;
    constexpr int PER = XTB * NZ;       // blocks per image
    constexpr int PITCH = 68;           // 64 gl + 4 pad
    constexpr int QGH = HWi / 64;       // (HWi/2) >> 5
    constexpr int NC2 = CIN / 16;       // K-chunks
    constexpr int NCH = 9 * NT;         // 1KB weight chunks per K-chunk
    constexpr int NPASS = (NCH + 7) / 8;
    constexpr int BUFB = NCH * 1024;    // bytes per staging buffer
    constexpr size_t EPIB = 8 * (16 * PITCH * 8) + 8 * 1024;  // 77824
    constexpr size_t LDSB = (2 * (size_t)BUFB > EPIB) ? 2 * (size_t)BUFB : EPIB;
    const half8 zero8 = {0, 0, 0, 0, 0, 0, 0, 0};

    __shared__ __align__(16) char ldsb[LDSB];

    const int tid  = threadIdx.x;
    const int wv   = tid >> 6;          // wave 0..7
    const int lane = tid & 63;
    const int l31  = lane & 31;
    const int kg   = lane >> 5;

    // XCD-aware decode: image owned by XCD (bid & 7), images sequential.
    const int bid   = blockIdx.x;
    const int xcd   = bid & 7;
    const int s     = bid >> 3;
    const int kslot = s / PER;          // image slot on this XCD (0..7)
    const int inner = s % PER;
    const int xti   = inner % XTB;
    const int zz    = inner / XTB;
    const int n0t   = zz * NT;
    const int b     = xcd * 8 + kslot;
    const int t0r   = xti * 8 + wv;     // this wave's tile
    const bool act  = t0r < TILES;
    const int t0    = act ? t0r : TILES - 1;   // clamp: lockstep dup work

    const int mp = t0 * 32 + l31;           // conv pixel (< HWi by clamp)
    const int py = mp / W, px = mp % W;
    const size_t xtb = (size_t)b * CIN * HWi;

    unsigned aoff[9];
    unsigned amask = 0;                 // bit t = tap valid
    #pragma unroll
    for (int ki = 0; ki < 3; ki++) {
        #pragma unroll
        for (int kj = 0; kj < 3; kj++) {
            int t  = ki * 3 + kj;
            int iy = py + ki - 1, ix = px + kj - 1;
            bool v = (iy >= 0 && iy < H && ix >= 0 && ix < W);
            int ps = v ? iy * W + ix : 0;
            aoff[t] = (unsigned)((ps >> 5) * KB * 256 + (ps & 31) * 8);
            amask |= (v ? 1u : 0u) << t;
        }
    }

    floatx16 acc[NT];
    #pragma unroll
    for (int i = 0; i < NT; i++)
        #pragma unroll
        for (int j = 0; j < 16; j++) acc[i][j] = 0.f;

    // ---- weight staging: chunk = t*NT + nt, 1KB each (2 kb x 32 x 8 fp16).
    auto stage = [&](int c2s, int buf) {
        #pragma unroll
        for (int it = 0; it < NPASS; it++) {
            int slot  = it * 8 + wv;
            int chunk = slot < NCH ? slot : slot - NCH;  // tail: benign dup
            int t  = chunk / NT;
            int nt = chunk % NT;
            const half_t* src = wf
                + (((size_t)t * (CO / 32) + (n0t + nt)) * KB + (size_t)c2s * 2) * 256
                + lane * 8;
            __builtin_amdgcn_global_load_lds(
                (const __attribute__((address_space(1))) unsigned*)src,
                (__attribute__((address_space(3))) unsigned*)(ldsb + buf * BUFB + chunk * 1024),
                16, 0, 0);
        }
    };

    stage(0, 0);
    asm volatile("s_waitcnt vmcnt(0)" ::: "memory");
    __syncthreads();

    for (int c2 = 0; c2 < NC2; c2++) {
        const int cur = c2 & 1;
        if (c2 + 1 < NC2) stage(c2 + 1, cur ^ 1);
        const unsigned kb = c2 * 2 + kg;
        #pragma unroll
        for (int t = 0; t < 9; t++) {
            const size_t au = xtb + aoff[t] + (size_t)kb * 256;
            half8 a = *(const half8*)(xt + au);
            if (!((amask >> t) & 1u)) a = zero8;
            #pragma unroll
            for (int nt = 0; nt < NT; nt++) {
                const half8 bv = *(const half8*)(ldsb + cur * BUFB
                                 + (t * NT + nt) * 1024 + kg * 512 + l31 * 16);
                acc[nt] = __builtin_amdgcn_mfma_f32_32x32x16_f16(a, bv, acc[nt], 0, 0, 0);
            }
        }
        if (c2 + 1 < NC2) {
            asm volatile("s_waitcnt vmcnt(0)" ::: "memory");
            __syncthreads();
        }
    }

    // main loop done on all waves before the epilogue reuses the LDS union.
    __syncthreads();

    if (!act) return;   // tail waves: no output (no further barriers below)

    // ---- transposed epilogue (per-wave regions in the LDS union) ----
    float2* offw = (float2*)(ldsb + (size_t)wv * (16 * PITCH * 8));
    uint_t* stgw = (uint_t*)(ldsb + 8 * (16 * PITCH * 8) + (size_t)wv * 1024);
    const int qb  = (t0 & 1) * 16;      // (q & 31) base
    const int qg0 = t0 >> 1;            // (q >> 5) for hlf = 0

    #pragma unroll
    for (int half = 0; half < NT / 2; half++) {
        // phase 1: this wave's 64 gl-rows of (oi,oj) into LDS [r2][gl].
        #pragma unroll
        for (int ntl = 0; ntl < 2; ntl++) {
            const int gl = ntl * 32 + l31;
            #pragma unroll
            for (int t = 0; t < 8; t++) {
                int r2w = (t & 1) + 2 * kg + 4 * (t >> 1);   // row >> 1
                offw[r2w * PITCH + gl] =
                    float2{acc[half * 2 + ntl][2 * t], acc[half * 2 + ntl][2 * t + 1]};
            }
        }
        asm volatile("s_waitcnt lgkmcnt(0)" ::: "memory");

        const int bc0 = n0t * 16 + half * 32;   // first channel of this half
        #pragma unroll
        for (int sc = 0; sc < 4; sc++) {        // 8 channels per super-chunk
            const int r2 = lane & 15;
            #pragma unroll
            for (int sub = 0; sub < 4; sub++) {
                const int gl  = sc * 16 + sub * 4 + (lane >> 4);
                float2 od = offw[r2 * PITCH + gl];
                const int hlf = (lane >> 4) & 1;
                const int c   = bc0 + sc * 8 + sub * 2 + kg;
                const int q   = hlf * (HWi / 2) + t0 * 16 + r2;
                const int qi = q / W, qj = q % W;
                float ci_ = fminf(fmaxf(od.x + (float)qi, 0.f), (float)(H - 1));
                float cj_ = fminf(fmaxf(od.y + (float)qj, 0.f), (float)(W - 1));
                float i0f = floorf(ci_), j0f = floorf(cj_);
                int i0 = (int)i0f, i1 = (int)ceilf(ci_);
                int j0 = (int)j0f;
                const half_t* gp = xl + xtb + (size_t)c * HWi;
                // pair loads: (i,j0) lo16, (i,j0+1) hi16; hi dead when dj==0.
                uint_t u0 = *(const uint_t*)(gp + i0 * W + j0);
                uint_t u1 = *(const uint_t*)(gp + i1 * W + j0);
                float v00 = h2f_lo(u0), v01 = h2f_hi(u0);
                float v10 = h2f_lo(u1), v11 = h2f_hi(u1);
                float di = ci_ - i0f, dj = cj_ - j0f;
                float top = v00 + di * (v10 - v00);
                float bot = v01 + di * (v11 - v01);
                float res = top + dj * (bot - top);
                stgw[hlf * 128 + r2 * 8 + (sub * 2 + kg)] = split_word(res);
            }
            asm volatile("s_waitcnt lgkmcnt(0)" ::: "memory");
            // dense 512B stores: 16 q x 8 c per hlf, packed-layout exact.
            const int cg = (bc0 >> 3) + sc;
            #pragma unroll
            for (int hlf = 0; hlf < 2; hlf++) {
                uint2v dd = *(const uint2v*)&stgw[hlf * 128 + 2 * lane];
                size_t dst = xtb + ((size_t)(hlf * QGH + qg0) * KB + cg) * 256
                           + (size_t)qb * 8 + 2 * lane;
                *(uint2v*)(outp + dst) = dd;
            }
        }
    }
}

// ---------------------------------------------------------------------------
// Value convs (BREL), r22 staged structure (verified): 512 thr = 8 waves =
// 8 pixel-tiles of ONE image; bh/bl weight planes double-buffered in LDS via
// global_load_lds(16B); XCD image-ownership decode. Bit-identical results.
// ---------------------------------------------------------------------------
template<int S, int W, int H, int CIN, int CO, int NT, int NZ>
__global__ __launch_bounds__(512, 4) void mfma_conv_g(
    const uint_t* __restrict__ xt,
    const ushort_t* __restrict__ wh, const ushort_t* __restrict__ wl,
    const float* __restrict__ bias, float* __restrict__ out)
{
    constexpr int Wo  = W / S, Ho = H / S;
    constexpr int HWo = Wo * Ho;
    constexpr int HWi = W * H;
    constexpr int KB  = CIN / 8;
    constexpr int TILES = (HWo + 31) / 32;
    constexpr int XTB = (TILES + 7) / 8;
    constexpr int PER = XTB * NZ;
    constexpr int NC2 = CIN / 16;
    constexpr int NCH = 9 * NT * 2;     // bh+bl 1KB chunks per K-chunk
    constexpr int NPASS = (NCH + 7) / 8;
    constexpr int BUFB = NCH * 1024;

    __shared__ __align__(16) char ldsb[2 * BUFB];

    const int tid  = threadIdx.x;
    const int wv   = tid >> 6;
    const int lane = tid & 63;
    const int l31  = lane & 31;
    const int kg   = lane >> 5;

    const int bid   = blockIdx.x;
    const int xcd   = bid & 7;
    const int s     = bid >> 3;
    const int kslot = s / PER;
    const int inner = s % PER;
    const int xti   = inner % XTB;
    const int zz    = inner / XTB;
    const int n0t   = zz * NT;
    const int b     = xcd * 8 + kslot;
    const int t0r   = xti * 8 + wv;
    const bool act  = t0r < TILES;
    const int t0    = act ? t0r : TILES - 1;

    const int mp  = t0 * 32 + l31;
    const int mpc = mp < HWo ? mp : HWo - 1;
    const int py  = mpc / Wo, px = mpc % Wo;
    const size_t xtb = (size_t)b * CIN * HWi;

    unsigned aoff[9];
    unsigned amask = 0;
    #pragma unroll
    for (int ki = 0; ki < 3; ki++) {
        #pragma unroll
        for (int kj = 0; kj < 3; kj++) {
            int t  = ki * 3 + kj;
            int iy = py * S + ki - 1, ix = px * S + kj - 1;
            bool v = (iy >= 0 && iy < H && ix >= 0 && ix < W);
            int ps = v ? iy * W + ix : 0;
            aoff[t] = (unsigned)((ps >> 5) * KB * 256 + (ps & 31) * 8);
            amask |= (v ? 1u : 0u) << t;
        }
    }

    floatx16 acc[NT];
    #pragma unroll
    for (int i = 0; i < NT; i++)
        #pragma unroll
        for (int j = 0; j < 16; j++) acc[i][j] = 0.f;

    // chunk = ((t*NT + nt)*2 + plane), 1KB each (2 kb x 32 x 8 ushort).
    auto stage = [&](int c2s, int buf) {
        #pragma unroll
        for (int it = 0; it < NPASS; it++) {
            int slot  = it * 8 + wv;
            int chunk = slot < NCH ? slot : slot - NCH;  // tail: benign dup
            int plane = chunk & 1;
            int tn = chunk >> 1;
            int t  = tn / NT;
            int nt = tn % NT;
            const ushort_t* srcp = (plane ? wl : wh)
                + (((size_t)t * (CO / 32) + (n0t + nt)) * KB + (size_t)c2s * 2) * 256
                + lane * 8;
            __builtin_amdgcn_global_load_lds(
                (const __attribute__((address_space(1))) unsigned*)srcp,
                (__attribute__((address_space(3))) unsigned*)(ldsb + buf * BUFB + chunk * 1024),
                16, 0, 0);
        }
    };

    stage(0, 0);
    asm volatile("s_waitcnt vmcnt(0)" ::: "memory");
    __syncthreads();

    for (int c2 = 0; c2 < NC2; c2++) {
        const int cur = c2 & 1;
        if (c2 + 1 < NC2) stage(c2 + 1, cur ^ 1);
        const unsigned kb = c2 * 2 + kg;
        #pragma unroll
        for (int t = 0; t < 9; t++) {
            const size_t au = xtb + aoff[t] + (size_t)kb * 256;
            uint4v w0 = *(const uint4v*)(xt + au);
            uint4v w1 = *(const uint4v*)(xt + au + 4);
            if (!((amask >> t) & 1u)) {
                w0 = uint4v{0, 0, 0, 0};
                w1 = uint4v{0, 0, 0, 0};
            }
            union { short8 s; uint_t u[4]; } uh, ul;
            uh.u[0] = (w0.x >> 16) | (w0.y & 0xFFFF0000u);
            uh.u[1] = (w0.z >> 16) | (w0.w & 0xFFFF0000u);
            uh.u[2] = (w1.x >> 16) | (w1.y & 0xFFFF0000u);
            uh.u[3] = (w1.z >> 16) | (w1.w & 0xFFFF0000u);
            ul.u[0] = (w0.x & 0xFFFFu) | (w0.y << 16);
            ul.u[1] = (w0.z & 0xFFFFu) | (w0.w << 16);
            ul.u[2] = (w1.x & 0xFFFFu) | (w1.y << 16);
            ul.u[3] = (w1.z & 0xFFFFu) | (w1.w << 16);
            short8 ah = uh.s, al = ul.s;
            #pragma unroll
            for (int nt = 0; nt < NT; nt++) {
                const char* bb = ldsb + cur * BUFB
                               + ((t * NT + nt) * 2) * 1024 + kg * 512 + l31 * 16;
                short8 bh = *(const short8*)bb;
                short8 bl = *(const short8*)(bb + 1024);
                floatx16 a = acc[nt];
                a = __builtin_amdgcn_mfma_f32_32x32x16_bf16(ah, bh, a, 0, 0, 0);
                a = __builtin_amdgcn_mfma_f32_32x32x16_bf16(ah, bl, a, 0, 0, 0);
                a = __builtin_amdgcn_mfma_f32_32x32x16_bf16(al, bh, a, 0, 0, 0);
                acc[nt] = a;
            }
        }
        if (c2 + 1 < NC2) {
            asm volatile("s_waitcnt vmcnt(0)" ::: "memory");
            __syncthreads();
        }
    }

    if (!act) return;

    #pragma unroll
    for (int nt = 0; nt < NT; nt++) {
        int co = (n0t + nt) * 32 + l31;
        float bv = bias[co];
        #pragma unroll
        for (int reg = 0; reg < 16; reg++) {
            int row = (reg & 3) + 8 * (reg >> 2) + 4 * kg;
            int p   = t0 * 32 + row;
            if (p < HWo)
                out[((size_t)b * CO + co) * HWo + p] = fmaxf(acc[nt][reg] + bv, 0.f);
        }
    }
}

// ---------------------------------------------------------------------------
// Vector direct 3x3 conv (kept only for conv11: Cin=1). Round 26: COPB 8->16
// (halves block count + patch-staging overhead; per-output accumulation
// order untouched -> bit-identical).
// ---------------------------------------------------------------------------
template<int STRIDE>
__global__ __launch_bounds__(256) void conv3x3_kernel(
    const float* __restrict__ in, const float* __restrict__ wgt,
    const float* __restrict__ bias, float* __restrict__ out,
    int B, int Cin, int H, int W, int Cout, int Ho, int Wo, int do_relu)
{
    constexpr int TILE = 28;
    constexpr int PR   = (TILE - 1) * STRIDE + 3;
    constexpr int PADW = (STRIDE == 1) ? 32 : 60;
    constexpr int COPB = 16;
    constexpr int RW   = STRIDE + 3;
    __shared__ float patch[PR * PADW];

    int cpg  = Cout / COPB;
    int bz   = blockIdx.z;
    int cog  = bz % cpg;
    int b    = bz / cpg;
    int co0  = cog * COPB;
    int tid  = threadIdx.x;
    int oy0  = blockIdx.y * TILE, ox0 = blockIdx.x * TILE;
    int iy0  = oy0 * STRIDE - 1,  ix0 = ox0 * STRIDE - 1;

    bool active = tid < 196;
    int ty = tid / 14, tx = tid % 14;
    int py = oy0 + 2 * ty, px = ox0 + 2 * tx;

    float acc[COPB][4];
    #pragma unroll
    for (int i = 0; i < COPB; i++) {
        float bv = bias ? bias[co0 + i] : 0.f;
        #pragma unroll
        for (int j = 0; j < 4; j++) acc[i][j] = bv;
    }

    const size_t HW = (size_t)H * W;
    for (int ci = 0; ci < Cin; ci++) {
        const float* ip = in + ((size_t)b * Cin + ci) * HW;
        for (int t = tid; t < PR * PADW; t += 256) {
            int sy = t / PADW, sx = t % PADW;
            float v = 0.f;
            int gy = iy0 + sy, gx = ix0 + sx;
            if (sx < PR && gy >= 0 && gy < H && gx >= 0 && gx < W)
                v = ip[(size_t)gy * W + gx];
            patch[t] = v;
        }
        __syncthreads();
        if (active) {
            float r[RW][RW];
            #pragma unroll
            for (int rr = 0; rr < RW; rr++) {
                int rowbase = (2 * ty * STRIDE + rr) * PADW + 2 * tx * STRIDE;
                if (STRIDE == 1) {
                    float2 a = *(const float2*)&patch[rowbase];
                    float2 c = *(const float2*)&patch[rowbase + 2];
                    r[rr][0] = a.x; r[rr][1] = a.y; r[rr][2] = c.x; r[rr][3] = c.y;
                } else {
                    float4 a = *(const float4*)&patch[rowbase];
                    r[rr][0] = a.x; r[rr][1] = a.y; r[rr][2] = a.z; r[rr][3] = a.w;
                    r[rr][4] = patch[rowbase + 4];
                }
            }
            const float* wb = wgt + ((size_t)co0 * Cin + ci) * 9;
            #pragma unroll
            for (int i = 0; i < COPB; i++) {
                const float* wp = wb + (size_t)i * Cin * 9;
                #pragma unroll
                for (int ki = 0; ki < 3; ki++)
                    #pragma unroll
                    for (int kj = 0; kj < 3; kj++) {
                        float w = wp[ki * 3 + kj];
                        acc[i][0] = fmaf(r[ki][kj],                   w, acc[i][0]);
                        acc[i][1] = fmaf(r[ki][kj + STRIDE],          w, acc[i][1]);
                        acc[i][2] = fmaf(r[ki + STRIDE][kj],          w, acc[i][2]);
                        acc[i][3] = fmaf(r[ki + STRIDE][kj + STRIDE], w, acc[i][3]);
                    }
            }
        }
        __syncthreads();
    }
    if (active) {
        #pragma unroll
        for (int rr = 0; rr < 2; rr++) {
            #pragma unroll
            for (int cc = 0; cc < 2; cc++) {
                int oy = py + rr, ox = px + cc;
                if (oy < Ho && ox < Wo) {
                    #pragma unroll
                    for (int i = 0; i < COPB; i++) {
                        float v = acc[i][rr * 2 + cc];
                        if (do_relu) v = fmaxf(v, 0.f);
                        out[(((size_t)b * Cout + co0 + i) * Ho + oy) * Wo + ox] = v;
                    }
                }
            }
        }
    }
}

// ---------------------------------------------------------------------------
__global__ __launch_bounds__(256) void bn_stats_kernel(
    const float* __restrict__ x, float* __restrict__ stats,
    int B, int C, int HW)
{
    int c = blockIdx.x;
    long long cnt = (long long)B * HW;
    long long step = (long long)gridDim.y * blockDim.x;
    float s = 0.f, s2 = 0.f;
    for (long long t = (long long)blockIdx.y * blockDim.x + threadIdx.x; t < cnt; t += step) {
        int b  = (int)(t / HW);
        int sp = (int)(t % HW);
        float v = x[((size_t)b * C + c) * (size_t)HW + sp];
        s += v; s2 += v * v;
    }
    for (int off = 32; off; off >>= 1) {
        s  += __shfl_down(s, off);
        s2 += __shfl_down(s2, off);
    }
    __shared__ float ls[4], ls2[4];
    int wave = threadIdx.x >> 6, lane = threadIdx.x & 63;
    if (lane == 0) { ls[wave] = s; ls2[wave] = s2; }
    __syncthreads();
    if (threadIdx.x == 0) {
        float ts = 0.f, ts2 = 0.f;
        for (int i = 0; i < 4; i++) { ts += ls[i]; ts2 += ls2[i]; }
        atomicAdd(&stats[c], ts);
        atomicAdd(&stats[C + c], ts2);
    }
}

// ---------------------------------------------------------------------------
__global__ void zero_kernel(float* __restrict__ p, int n)
{
    int i = blockIdx.x * blockDim.x + threadIdx.x;
    if (i < n) p[i] = 0.f;
}

// ---------------------------------------------------------------------------
__global__ __launch_bounds__(256) void pool_kernel(
    const float* __restrict__ x, const float* __restrict__ stats,
    const float* __restrict__ g, const float* __restrict__ be,
    float inv_cnt, float* __restrict__ out, int C, int HW)
{
    int bc = blockIdx.x;
    int c  = bc % C;
    const float* xp = x + (size_t)bc * HW;
    float s = 0.f;
    for (int i = threadIdx.x; i < HW; i += blockDim.x) s += xp[i];
    for (int off = 32; off; off >>= 1) s += __shfl_down(s, off);
    __shared__ float ls[4];
    int wave = threadIdx.x >> 6, lane = threadIdx.x & 63;
    if (lane == 0) ls[wave] = s;
    __syncthreads();
    if (threadIdx.x == 0) {
        float t = 0.f;
        for (int i = 0; i < 4; i++) t += ls[i];
        float mean = t / (float)HW;
        float m  = stats[c] * inv_cnt;
        float vv = stats[C + c] * inv_cnt - m * m;
        float sc = g[c] / sqrtf(vv + BN_EPS);
        float sh = be[c] - m * sc;
        out[bc] = mean * sc + sh;
    }
}

// ---------------------------------------------------------------------------
__global__ __launch_bounds__(128) void fc_softmax_kernel(
    const float* __restrict__ pool, const float* __restrict__ wfc,
    const float* __restrict__ bfc, float* __restrict__ out)
{
    int b = blockIdx.x;
    __shared__ float row[128];
    __shared__ float logits[10];
    int tid = threadIdx.x;
    row[tid] = pool[b * 128 + tid];
    __syncthreads();
    if (tid < 10) {
        float s = bfc[tid];
        for (int k = 0; k < 128; k++) s = fmaf(row[k], wfc[tid * 128 + k], s);
        logits[tid] = s;
    }
    __syncthreads();
    if (tid < 10) {
        float mx = logits[0];
        for (int i = 1; i < 10; i++) mx = fmaxf(mx, logits[i]);
        float sum = 0.f;
        for (int i = 0; i < 10; i++) sum += expf(logits[i] - mx);
        out[b * 10 + tid] = expf(logits[tid] - mx) / sum;
    }
}

// ---------------------------------------------------------------------------
// Region ping-pong: two 102.8 MB regions R0/R1 alternate between
// {fp32 conv output} -> {tiled+linear fp16 planes} -> {packed u32 conv input}.
// Live-range audit per stage done r17; no overlap.
// ---------------------------------------------------------------------------
extern "C" void kernel_launch(void* const* d_in, const int* in_sizes, int n_in,
                              void* d_out, int out_size, void* d_ws, size_t ws_size,
                              hipStream_t stream)
{
    const float* x      = (const float*)d_in[0];
    const float* w11    = (const float*)d_in[1];
    const float* b11    = (const float*)d_in[2];
    const float* g11    = (const float*)d_in[3];
    const float* be11   = (const float*)d_in[4];
    const float* woff12 = (const float*)d_in[5];
    const float* w12    = (const float*)d_in[6];
    const float* b12    = (const float*)d_in[7];
    const float* g12    = (const float*)d_in[8];
    const float* be12   = (const float*)d_in[9];
    const float* woff21 = (const float*)d_in[10];
    const float* w21    = (const float*)d_in[11];
    const float* b21    = (const float*)d_in[12];
    const float* g21    = (const float*)d_in[13];
    const float* be21   = (const float*)d_in[14];
    const float* woff22 = (const float*)d_in[15];
    const float* w22    = (const float*)d_in[16];
    const float* b22    = (const float*)d_in[17];
    const float* g22    = (const float*)d_in[18];
    const float* be22   = (const float*)d_in[19];
    const float* wfc    = (const float*)d_in[20];
    const float* bfc    = (const float*)d_in[21];
    float* out = (float*)d_out;

    float* ws    = (float*)d_ws;
    const size_t SZ_B = 25690112;   // 64*32*112*112 = 64*128*56*56 elements

    // Region 0
    float*  R0f = ws;
    uint_t* R0u = (uint_t*)R0f;
    half_t* R0h = (half_t*)R0f;          // tiled fp16 plane
    half_t* R0l = R0h + SZ_B;            // linear fp16 plane
    float* stats = R0f + SZ_B;           // 512
    float* aff   = stats + 512;          // 512
    float* poolb = aff + 512;            // 8192
    // Region 1
    uint_t* R1u = (uint_t*)(poolb + 8192);
    float*  R1f = (float*)R1u;
    half_t* R1h = (half_t*)R1u;
    half_t* R1l = R1h + SZ_B;
    // Weights
    ushort_t* warena = (ushort_t*)(R1u + SZ_B);
    const size_t W12 = 9 * 64 * 32;
    const size_t W21 = 9 * 128 * 64;
    const size_t W22c = 9 * 128 * 128;
    const size_t W12o = 9 * 64 * 32;
    const size_t W21o = 9 * 128 * 64;
    ushort_t* wc12h = warena;          ushort_t* wc12l = wc12h + W12;
    ushort_t* wc21h = wc12l + W12;     ushort_t* wc21l = wc21h + W21;
    ushort_t* wc22h = wc21l + W21;     ushort_t* wc22l = wc22h + W22c;
    half_t* wpf12 = (half_t*)(wc22l + W22c);
    half_t* wpf21 = wpf12 + W12o;
    half_t* wpf22 = wpf21 + W21o;

    const int B = 64;

    // ---- weight prep ----
    prep_w_kernel<<<(9*64*32   + 255)/256, 256, 0, stream>>>(w12, wc12h, wc12l, 64, 32);
    prep_w_kernel<<<(9*128*64  + 255)/256, 256, 0, stream>>>(w21, wc21h, wc21l, 128, 64);
    prep_w_kernel<<<(9*128*128 + 255)/256, 256, 0, stream>>>(w22, wc22h, wc22l, 128, 128);
    prep_wf16_kernel<<<(9*64*32   + 255)/256, 256, 0, stream>>>(woff12, wpf12, 64, 32);
    prep_wf16_kernel<<<(9*128*64  + 255)/256, 256, 0, stream>>>(woff21, wpf21, 128, 64);
    prep_wf16_kernel<<<(9*256*128 + 255)/256, 256, 0, stream>>>(woff22, wpf22, 256, 128);

    // ---- Layer 1.1: conv(1->32, s1)+relu -> R0f; stats; finalize ----
    conv3x3_kernel<1><<<dim3(4, 4, B * (32 / 16)), 256, 0, stream>>>(
        x, w11, b11, R0f, B, 1, 112, 112, 32, 112, 112, 1);
    zero_kernel<<<2, 256, 0, stream>>>(stats, 512);
    bn_stats_kernel<<<dim3(32, 64), 256, 0, stream>>>(R0f, stats, B, 32, 12544);
    bn_finalize_kernel<<<1, 256, 0, stream>>>(stats, g11, be11, 1.f/(64.f*12544.f), aff, 32);

    // ---- deform12: pack BN(1.1) R0f -> R1 planes; deform -> R0 packed ----
    pack_af16_kernel<<<(B*4*12544 + 255)/256, 256, 0, stream>>>(
        R0f, aff, R1h, R1l, 32, 12544, B*4*12544);
    mfma_deform_g<112, 112, 32, 64, 2, 1>
        <<<dim3(64 * 49), 512, 0, stream>>>(R1h, R1l, wpf12, R0u);

    // ---- Layer 1.2 (MFMA s2, staged): conv(R0 packed) -> R1f ----
    mfma_conv_g<2, 112, 112, 32, 64, 2, 1>
        <<<dim3(64 * 13), 512, 0, stream>>>(R0u, wc12h, wc12l, b12, R1f);
    zero_kernel<<<2, 256, 0, stream>>>(stats, 512);
    bn_stats_kernel<<<dim3(64, 64), 256, 0, stream>>>(R1f, stats, B, 64, 3136);
    bn_finalize_kernel<<<1, 256, 0, stream>>>(stats, g12, be12, 1.f/(64.f*3136.f), aff, 64);

    // ---- deform21: pack BN(1.2) R1f -> R0 planes; deform -> R1 packed ----
    pack_af16_kernel<<<(B*8*3136 + 255)/256, 256, 0, stream>>>(
        R1f, aff, R0h, R0l, 64, 3136, B*8*3136);
    mfma_deform_g<56, 56, 64, 128, 4, 1>
        <<<dim3(64 * 13), 512, 0, stream>>>(R0h, R0l, wpf21, R1u);

    // ---- Layer 2.1 (MFMA s1, staged): conv(R1 packed) -> R0f ----
    mfma_conv_g<1, 56, 56, 64, 128, 2, 2>
        <<<dim3(64 * 26), 512, 0, stream>>>(R1u, wc21h, wc21l, b21, R0f);
    zero_kernel<<<2, 256, 0, stream>>>(stats, 512);
    bn_stats_kernel<<<dim3(128, 64), 256, 0, stream>>>(R0f, stats, B, 128, 3136);
    bn_finalize_kernel<<<1, 256, 0, stream>>>(stats, g21, be21, 1.f/(64.f*3136.f), aff, 128);

    // ---- deform22: pack BN(2.1) R0f -> R1 planes; deform -> R0 packed ----
    pack_af16_kernel<<<(B*16*3136 + 255)/256, 256, 0, stream>>>(
        R0f, aff, R1h, R1l, 128, 3136, B*16*3136);
    mfma_deform_g<56, 56, 128, 256, 4, 2>
        <<<dim3(64 * 26), 512, 0, stream>>>(R1h, R1l, wpf22, R0u);

    // ---- Layer 2.2 (MFMA s2, staged): conv(R0 packed) -> R1f ----
    mfma_conv_g<2, 56, 56, 128, 128, 2, 2>
        <<<dim3(64 * 8), 512, 0, stream>>>(R0u, wc22h, wc22l, b22, R1f);
    zero_kernel<<<2, 256, 0, stream>>>(stats, 512);
    bn_stats_kernel<<<dim3(128, 64), 256, 0, stream>>>(R1f, stats, B, 128, 784);

    // ---- Pool (BN(2.2) fused) + FC + softmax ----
    pool_kernel<<<B * 128, 256, 0, stream>>>(
        R1f, stats, g22, be22, 1.f/(64.f*784.f), poolb, 128, 784);
    fc_softmax_kernel<<<B, 128, 0, stream>>>(poolb, wfc, bfc, out);
}

// Round 12
// 1037.260 us; speedup vs baseline: 1.0780x; 1.0780x over previous
//
#include <hip/hip_runtime.h>
#include <math.h>

#define BN_EPS 1e-5f

typedef unsigned short ushort_t;
typedef unsigned int uint_t;
typedef _Float16 half_t;
typedef __attribute__((ext_vector_type(8))) short short8;     // 8 bf16 (4 VGPR)
typedef __attribute__((ext_vector_type(8))) _Float16 half8;   // 8 fp16 (4 VGPR)
typedef __attribute__((ext_vector_type(4))) unsigned uint4v;  // 4 dwords
typedef __attribute__((ext_vector_type(2))) unsigned uint2v;  // 2 dwords
typedef __attribute__((ext_vector_type(16))) float floatx16;  // MFMA 32x32 acc

// Split fp32 into bf16 hi (bit-truncate, exact) + bf16 lo (truncated remainder).
__device__ __forceinline__ void split_bf16(float v, ushort_t& h, ushort_t& l) {
    unsigned u = __float_as_uint(v);
    float fhi = __uint_as_float(u & 0xFFFF0000u);
    h = (ushort_t)(u >> 16);
    l = (ushort_t)(__float_as_uint(v - fhi) >> 16);
}

// Interleaved word: hi in high16, lo in low16.
__device__ __forceinline__ uint_t split_word(float v) {
    ushort_t h, l;
    split_bf16(v, h, l);
    return ((uint_t)h << 16) | (uint_t)l;
}

__device__ __forceinline__ float h2f_lo(uint_t u) {
    union { ushort_t s; half_t h; } cv; cv.s = (ushort_t)(u & 0xFFFFu);
    return (float)cv.h;
}
__device__ __forceinline__ float h2f_hi(uint_t u) {
    union { ushort_t s; half_t h; } cv; cv.s = (ushort_t)(u >> 16);
    return (float)cv.h;
}

// ---------------------------------------------------------------------------
// Weight prep (value convs): OIHW fp32 -> tiled [tap][o>>5][i>>3][o&31][i&7]
// bf16 hi/lo planes (split-bf16 3-MFMA path).
// ---------------------------------------------------------------------------
__global__ __launch_bounds__(256) void prep_w_kernel(
    const float* __restrict__ w, ushort_t* __restrict__ hi,
    ushort_t* __restrict__ lo, int O, int I)
{
    int idx = blockIdx.x * 256 + threadIdx.x;
    int n = 9 * O * I;
    if (idx >= n) return;
    int i = idx % I;
    int rest = idx / I;
    int o = rest % O;
    int t = rest / O;
    float v = w[((size_t)o * I + i) * 9 + t];
    size_t d = ((((size_t)t * (O / 32) + (o >> 5)) * (I / 8) + (i >> 3)) * 32
                + (o & 31)) * 8 + (i & 7);
    split_bf16(v, hi[d], lo[d]);
}

// ---------------------------------------------------------------------------
// Weight prep (deform offset convs): OIHW fp32 -> tiled fp16 single plane.
// ---------------------------------------------------------------------------
__global__ __launch_bounds__(256) void prep_wf16_kernel(
    const float* __restrict__ w, half_t* __restrict__ o, int O, int I)
{
    int idx = blockIdx.x * 256 + threadIdx.x;
    int n = 9 * O * I;
    if (idx >= n) return;
    int i = idx % I;
    int rest = idx / I;
    int oo = rest % O;
    int t = rest / O;
    float v = w[((size_t)oo * I + i) * 9 + t];
    size_t d = ((((size_t)t * (O / 32) + (oo >> 5)) * (I / 8) + (i >> 3)) * 32
                + (oo & 31)) * 8 + (i & 7);
    o[d] = (half_t)v;
}

// ---------------------------------------------------------------------------
// A prep, deform layers: NCHW fp32 + BN affine -> tiled fp16 plane (MFMA A)
// + LINEAR fp16 plane [b][c][H*W] (bilinear gather source).
// ---------------------------------------------------------------------------
__global__ __launch_bounds__(256) void pack_af16_kernel(
    const float* __restrict__ x, const float* __restrict__ aff,
    half_t* __restrict__ xt, half_t* __restrict__ xl,
    int C, int HW, int total)
{
    int idx = blockIdx.x * 256 + threadIdx.x;
    if (idx >= total) return;
    int p = idx % HW;
    int rest = idx / HW;
    int cg = rest % (C / 8);
    int b  = rest / (C / 8);
    const float* xp = x + ((size_t)b * C + cg * 8) * HW + p;
    half8 hv;
    #pragma unroll
    for (int j = 0; j < 8; j++) {
        int c = cg * 8 + j;
        float v = fmaf(xp[(size_t)j * HW], aff[2 * c], aff[2 * c + 1]);
        hv[j] = (half_t)v;
        xl[((size_t)b * C + c) * HW + p] = hv[j];
    }
    size_t base = (size_t)b * C * HW + ((size_t)(p >> 5) * (C / 8) + cg) * 256
                + (size_t)(p & 31) * 8;
    *(half8*)(xt + base) = hv;
}

// ---------------------------------------------------------------------------
__global__ void bn_finalize_kernel(
    const float* __restrict__ stats, const float* __restrict__ g,
    const float* __restrict__ be, float inv_cnt, float* __restrict__ aff, int C)
{
    int c = threadIdx.x;
    if (c < C) {
        float m  = stats[c] * inv_cnt;
        float vv = stats[C + c] * inv_cnt - m * m;
        float sc = g[c] / sqrtf(vv + BN_EPS);
        aff[2 * c]     = sc;
        aff[2 * c + 1] = be[c] - m * sc;
    }
}

// ---------------------------------------------------------------------------
// DEFORM kernel (fp16): LDS-staged weights, 8-wave blocks, one image per
// block, XCD-aware decode, transposed epilogue. This is the r7-verified
// configuration (best total 1045.6us): PITCH 68 / stg pitch 8 — the r25
// bank-conflict re-pitch reduced conflicts 6.4M->2.4M but did NOT help
// (epilogue is gather-latency bound); reverted permanently.
// ---------------------------------------------------------------------------
template<int W, int H, int CIN, int CO, int NT, int NZ>
__global__ __launch_bounds__(512, 4) void mfma_deform_g(
    const half_t* __restrict__ xt, const half_t* __restrict__ xl,
    const half_t* __restrict__ wf, uint_t* __restrict__ outp)
{
    constexpr int HWi = W * H;
    constexpr int KB  = CIN / 8;
    constexpr int TILES = HWi / 32;     // 32-pixel tiles per image
    constexpr int XTB = (TILES + 7) / 8;
    constexpr int PER = XTB * NZ;       // blocks per image
    constexpr int PITCH = 68;           // 64 gl + 4 pad
    constexpr int QGH = HWi / 64;       // (HWi/2) >> 5
    constexpr int NC2 = CIN / 16;       // K-chunks
    constexpr int NCH = 9 * NT;         // 1KB weight chunks per K-chunk
    constexpr int NPASS = (NCH + 7) / 8;
    constexpr int BUFB = NCH * 1024;    // bytes per staging buffer
    constexpr size_t EPIB = 8 * (16 * PITCH * 8) + 8 * 1024;  // 77824
    constexpr size_t LDSB = (2 * (size_t)BUFB > EPIB) ? 2 * (size_t)BUFB : EPIB;
    const half8 zero8 = {0, 0, 0, 0, 0, 0, 0, 0};

    __shared__ __align__(16) char ldsb[LDSB];

    const int tid  = threadIdx.x;
    const int wv   = tid >> 6;          // wave 0..7
    const int lane = tid & 63;
    const int l31  = lane & 31;
    const int kg   = lane >> 5;

    // XCD-aware decode: image owned by XCD (bid & 7), images sequential.
    const int bid   = blockIdx.x;
    const int xcd   = bid & 7;
    const int s     = bid >> 3;
    const int kslot = s / PER;          // image slot on this XCD (0..7)
    const int inner = s % PER;
    const int xti   = inner % XTB;
    const int zz    = inner / XTB;
    const int n0t   = zz * NT;
    const int b     = xcd * 8 + kslot;
    const int t0r   = xti * 8 + wv;     // this wave's tile
    const bool act  = t0r < TILES;
    const int t0    = act ? t0r : TILES - 1;   // clamp: lockstep dup work

    const int mp = t0 * 32 + l31;           // conv pixel (< HWi by clamp)
    const int py = mp / W, px = mp % W;
    const size_t xtb = (size_t)b * CIN * HWi;

    unsigned aoff[9];
    unsigned amask = 0;                 // bit t = tap valid
    #pragma unroll
    for (int ki = 0; ki < 3; ki++) {
        #pragma unroll
        for (int kj = 0; kj < 3; kj++) {
            int t  = ki * 3 + kj;
            int iy = py + ki - 1, ix = px + kj - 1;
            bool v = (iy >= 0 && iy < H && ix >= 0 && ix < W);
            int ps = v ? iy * W + ix : 0;
            aoff[t] = (unsigned)((ps >> 5) * KB * 256 + (ps & 31) * 8);
            amask |= (v ? 1u : 0u) << t;
        }
    }

    floatx16 acc[NT];
    #pragma unroll
    for (int i = 0; i < NT; i++)
        #pragma unroll
        for (int j = 0; j < 16; j++) acc[i][j] = 0.f;

    // ---- weight staging: chunk = t*NT + nt, 1KB each (2 kb x 32 x 8 fp16).
    auto stage = [&](int c2s, int buf) {
        #pragma unroll
        for (int it = 0; it < NPASS; it++) {
            int slot  = it * 8 + wv;
            int chunk = slot < NCH ? slot : slot - NCH;  // tail: benign dup
            int t  = chunk / NT;
            int nt = chunk % NT;
            const half_t* src = wf
                + (((size_t)t * (CO / 32) + (n0t + nt)) * KB + (size_t)c2s * 2) * 256
                + lane * 8;
            __builtin_amdgcn_global_load_lds(
                (const __attribute__((address_space(1))) unsigned*)src,
                (__attribute__((address_space(3))) unsigned*)(ldsb + buf * BUFB + chunk * 1024),
                16, 0, 0);
        }
    };

    stage(0, 0);
    asm volatile("s_waitcnt vmcnt(0)" ::: "memory");
    __syncthreads();

    for (int c2 = 0; c2 < NC2; c2++) {
        const int cur = c2 & 1;
        if (c2 + 1 < NC2) stage(c2 + 1, cur ^ 1);
        const unsigned kb = c2 * 2 + kg;
        #pragma unroll
        for (int t = 0; t < 9; t++) {
            const size_t au = xtb + aoff[t] + (size_t)kb * 256;
            half8 a = *(const half8*)(xt + au);
            if (!((amask >> t) & 1u)) a = zero8;
            #pragma unroll
            for (int nt = 0; nt < NT; nt++) {
                const half8 bv = *(const half8*)(ldsb + cur * BUFB
                                 + (t * NT + nt) * 1024 + kg * 512 + l31 * 16);
                acc[nt] = __builtin_amdgcn_mfma_f32_32x32x16_f16(a, bv, acc[nt], 0, 0, 0);
            }
        }
        if (c2 + 1 < NC2) {
            asm volatile("s_waitcnt vmcnt(0)" ::: "memory");
            __syncthreads();
        }
    }

    // main loop done on all waves before the epilogue reuses the LDS union.
    __syncthreads();

    if (!act) return;   // tail waves: no output (no further barriers below)

    // ---- transposed epilogue (per-wave regions in the LDS union) ----
    float2* offw = (float2*)(ldsb + (size_t)wv * (16 * PITCH * 8));
    uint_t* stgw = (uint_t*)(ldsb + 8 * (16 * PITCH * 8) + (size_t)wv * 1024);
    const int qb  = (t0 & 1) * 16;      // (q & 31) base
    const int qg0 = t0 >> 1;            // (q >> 5) for hlf = 0

    #pragma unroll
    for (int half = 0; half < NT / 2; half++) {
        // phase 1: this wave's 64 gl-rows of (oi,oj) into LDS [r2][gl].
        #pragma unroll
        for (int ntl = 0; ntl < 2; ntl++) {
            const int gl = ntl * 32 + l31;
            #pragma unroll
            for (int t = 0; t < 8; t++) {
                int r2w = (t & 1) + 2 * kg + 4 * (t >> 1);   // row >> 1
                offw[r2w * PITCH + gl] =
                    float2{acc[half * 2 + ntl][2 * t], acc[half * 2 + ntl][2 * t + 1]};
            }
        }
        asm volatile("s_waitcnt lgkmcnt(0)" ::: "memory");

        const int bc0 = n0t * 16 + half * 32;   // first channel of this half
        #pragma unroll
        for (int sc = 0; sc < 4; sc++) {        // 8 channels per super-chunk
            const int r2 = lane & 15;
            #pragma unroll
            for (int sub = 0; sub < 4; sub++) {
                const int gl  = sc * 16 + sub * 4 + (lane >> 4);
                float2 od = offw[r2 * PITCH + gl];
                const int hlf = (lane >> 4) & 1;
                const int c   = bc0 + sc * 8 + sub * 2 + kg;
                const int q   = hlf * (HWi / 2) + t0 * 16 + r2;
                const int qi = q / W, qj = q % W;
                float ci_ = fminf(fmaxf(od.x + (float)qi, 0.f), (float)(H - 1));
                float cj_ = fminf(fmaxf(od.y + (float)qj, 0.f), (float)(W - 1));
                float i0f = floorf(ci_), j0f = floorf(cj_);
                int i0 = (int)i0f, i1 = (int)ceilf(ci_);
                int j0 = (int)j0f;
                const half_t* gp = xl + xtb + (size_t)c * HWi;
                // pair loads: (i,j0) lo16, (i,j0+1) hi16; hi dead when dj==0.
                uint_t u0 = *(const uint_t*)(gp + i0 * W + j0);
                uint_t u1 = *(const uint_t*)(gp + i1 * W + j0);
                float v00 = h2f_lo(u0), v01 = h2f_hi(u0);
                float v10 = h2f_lo(u1), v11 = h2f_hi(u1);
                float di = ci_ - i0f, dj = cj_ - j0f;
                float top = v00 + di * (v10 - v00);
                float bot = v01 + di * (v11 - v01);
                float res = top + dj * (bot - top);
                stgw[hlf * 128 + r2 * 8 + (sub * 2 + kg)] = split_word(res);
            }
            asm volatile("s_waitcnt lgkmcnt(0)" ::: "memory");
            // dense 512B stores: 16 q x 8 c per hlf, packed-layout exact.
            const int cg = (bc0 >> 3) + sc;
            #pragma unroll
            for (int hlf = 0; hlf < 2; hlf++) {
                uint2v dd = *(const uint2v*)&stgw[hlf * 128 + 2 * lane];
                size_t dst = xtb + ((size_t)(hlf * QGH + qg0) * KB + cg) * 256
                           + (size_t)qb * 8 + 2 * lane;
                *(uint2v*)(outp + dst) = dd;
            }
        }
    }
}

// ---------------------------------------------------------------------------
// Value convs (BREL), staged structure (verified): 512 thr = 8 waves =
// 8 pixel-tiles of ONE image; bh/bl weight planes double-buffered in LDS via
// global_load_lds(16B); XCD image-ownership decode. Bit-identical results.
// ---------------------------------------------------------------------------
template<int S, int W, int H, int CIN, int CO, int NT, int NZ>
__global__ __launch_bounds__(512, 4) void mfma_conv_g(
    const uint_t* __restrict__ xt,
    const ushort_t* __restrict__ wh, const ushort_t* __restrict__ wl,
    const float* __restrict__ bias, float* __restrict__ out)
{
    constexpr int Wo  = W / S, Ho = H / S;
    constexpr int HWo = Wo * Ho;
    constexpr int HWi = W * H;
    constexpr int KB  = CIN / 8;
    constexpr int TILES = (HWo + 31) / 32;
    constexpr int XTB = (TILES + 7) / 8;
    constexpr int PER = XTB * NZ;
    constexpr int NC2 = CIN / 16;
    constexpr int NCH = 9 * NT * 2;     // bh+bl 1KB chunks per K-chunk
    constexpr int NPASS = (NCH + 7) / 8;
    constexpr int BUFB = NCH * 1024;

    __shared__ __align__(16) char ldsb[2 * BUFB];

    const int tid  = threadIdx.x;
    const int wv   = tid >> 6;
    const int lane = tid & 63;
    const int l31  = lane & 31;
    const int kg   = lane >> 5;

    const int bid   = blockIdx.x;
    const int xcd   = bid & 7;
    const int s     = bid >> 3;
    const int kslot = s / PER;
    const int inner = s % PER;
    const int xti   = inner % XTB;
    const int zz    = inner / XTB;
    const int n0t   = zz * NT;
    const int b     = xcd * 8 + kslot;
    const int t0r   = xti * 8 + wv;
    const bool act  = t0r < TILES;
    const int t0    = act ? t0r : TILES - 1;

    const int mp  = t0 * 32 + l31;
    const int mpc = mp < HWo ? mp : HWo - 1;
    const int py  = mpc / Wo, px = mpc % Wo;
    const size_t xtb = (size_t)b * CIN * HWi;

    unsigned aoff[9];
    unsigned amask = 0;
    #pragma unroll
    for (int ki = 0; ki < 3; ki++) {
        #pragma unroll
        for (int kj = 0; kj < 3; kj++) {
            int t  = ki * 3 + kj;
            int iy = py * S + ki - 1, ix = px * S + kj - 1;
            bool v = (iy >= 0 && iy < H && ix >= 0 && ix < W);
            int ps = v ? iy * W + ix : 0;
            aoff[t] = (unsigned)((ps >> 5) * KB * 256 + (ps & 31) * 8);
            amask |= (v ? 1u : 0u) << t;
        }
    }

    floatx16 acc[NT];
    #pragma unroll
    for (int i = 0; i < NT; i++)
        #pragma unroll
        for (int j = 0; j < 16; j++) acc[i][j] = 0.f;

    // chunk = ((t*NT + nt)*2 + plane), 1KB each (2 kb x 32 x 8 ushort).
    auto stage = [&](int c2s, int buf) {
        #pragma unroll
        for (int it = 0; it < NPASS; it++) {
            int slot  = it * 8 + wv;
            int chunk = slot < NCH ? slot : slot - NCH;  // tail: benign dup
            int plane = chunk & 1;
            int tn = chunk >> 1;
            int t  = tn / NT;
            int nt = tn % NT;
            const ushort_t* srcp = (plane ? wl : wh)
                + (((size_t)t * (CO / 32) + (n0t + nt)) * KB + (size_t)c2s * 2) * 256
                + lane * 8;
            __builtin_amdgcn_global_load_lds(
                (const __attribute__((address_space(1))) unsigned*)srcp,
                (__attribute__((address_space(3))) unsigned*)(ldsb + buf * BUFB + chunk * 1024),
                16, 0, 0);
        }
    };

    stage(0, 0);
    asm volatile("s_waitcnt vmcnt(0)" ::: "memory");
    __syncthreads();

    for (int c2 = 0; c2 < NC2; c2++) {
        const int cur = c2 & 1;
        if (c2 + 1 < NC2) stage(c2 + 1, cur ^ 1);
        const unsigned kb = c2 * 2 + kg;
        #pragma unroll
        for (int t = 0; t < 9; t++) {
            const size_t au = xtb + aoff[t] + (size_t)kb * 256;
            uint4v w0 = *(const uint4v*)(xt + au);
            uint4v w1 = *(const uint4v*)(xt + au + 4);
            if (!((amask >> t) & 1u)) {
                w0 = uint4v{0, 0, 0, 0};
                w1 = uint4v{0, 0, 0, 0};
            }
            union { short8 s; uint_t u[4]; } uh, ul;
            uh.u[0] = (w0.x >> 16) | (w0.y & 0xFFFF0000u);
            uh.u[1] = (w0.z >> 16) | (w0.w & 0xFFFF0000u);
            uh.u[2] = (w1.x >> 16) | (w1.y & 0xFFFF0000u);
            uh.u[3] = (w1.z >> 16) | (w1.w & 0xFFFF0000u);
            ul.u[0] = (w0.x & 0xFFFFu) | (w0.y << 16);
            ul.u[1] = (w0.z & 0xFFFFu) | (w0.w << 16);
            ul.u[2] = (w1.x & 0xFFFFu) | (w1.y << 16);
            ul.u[3] = (w1.z & 0xFFFFu) | (w1.w << 16);
            short8 ah = uh.s, al = ul.s;
            #pragma unroll
            for (int nt = 0; nt < NT; nt++) {
                const char* bb = ldsb + cur * BUFB
                               + ((t * NT + nt) * 2) * 1024 + kg * 512 + l31 * 16;
                short8 bh = *(const short8*)bb;
                short8 bl = *(const short8*)(bb + 1024);
                floatx16 a = acc[nt];
                a = __builtin_amdgcn_mfma_f32_32x32x16_bf16(ah, bh, a, 0, 0, 0);
                a = __builtin_amdgcn_mfma_f32_32x32x16_bf16(ah, bl, a, 0, 0, 0);
                a = __builtin_amdgcn_mfma_f32_32x32x16_bf16(al, bh, a, 0, 0, 0);
                acc[nt] = a;
            }
        }
        if (c2 + 1 < NC2) {
            asm volatile("s_waitcnt vmcnt(0)" ::: "memory");
            __syncthreads();
        }
    }

    if (!act) return;

    #pragma unroll
    for (int nt = 0; nt < NT; nt++) {
        int co = (n0t + nt) * 32 + l31;
        float bv = bias[co];
        #pragma unroll
        for (int reg = 0; reg < 16; reg++) {
            int row = (reg & 3) + 8 * (reg >> 2) + 4 * kg;
            int p   = t0 * 32 + row;
            if (p < HWo)
                out[((size_t)b * CO + co) * HWo + p] = fmaxf(acc[nt][reg] + bv, 0.f);
        }
    }
}

// ---------------------------------------------------------------------------
// Vector direct 3x3 conv (kept only for conv11: Cin=1). COPB 8 — the r26
// COPB-16 variant regressed (half the blocks, 2x serial work per block).
// ---------------------------------------------------------------------------
template<int STRIDE>
__global__ __launch_bounds__(256) void conv3x3_kernel(
    const float* __restrict__ in, const float* __restrict__ wgt,
    const float* __restrict__ bias, float* __restrict__ out,
    int B, int Cin, int H, int W, int Cout, int Ho, int Wo, int do_relu)
{
    constexpr int TILE = 28;
    constexpr int PR   = (TILE - 1) * STRIDE + 3;
    constexpr int PADW = (STRIDE == 1) ? 32 : 60;
    constexpr int COPB = 8;
    constexpr int RW   = STRIDE + 3;
    __shared__ float patch[PR * PADW];

    int cpg  = Cout / COPB;
    int bz   = blockIdx.z;
    int cog  = bz % cpg;
    int b    = bz / cpg;
    int co0  = cog * COPB;
    int tid  = threadIdx.x;
    int oy0  = blockIdx.y * TILE, ox0 = blockIdx.x * TILE;
    int iy0  = oy0 * STRIDE - 1,  ix0 = ox0 * STRIDE - 1;

    bool active = tid < 196;
    int ty = tid / 14, tx = tid % 14;
    int py = oy0 + 2 * ty, px = ox0 + 2 * tx;

    float acc[COPB][4];
    #pragma unroll
    for (int i = 0; i < COPB; i++) {
        float bv = bias ? bias[co0 + i] : 0.f;
        #pragma unroll
        for (int j = 0; j < 4; j++) acc[i][j] = bv;
    }

    const size_t HW = (size_t)H * W;
    for (int ci = 0; ci < Cin; ci++) {
        const float* ip = in + ((size_t)b * Cin + ci) * HW;
        for (int t = tid; t < PR * PADW; t += 256) {
            int sy = t / PADW, sx = t % PADW;
            float v = 0.f;
            int gy = iy0 + sy, gx = ix0 + sx;
            if (sx < PR && gy >= 0 && gy < H && gx >= 0 && gx < W)
                v = ip[(size_t)gy * W + gx];
            patch[t] = v;
        }
        __syncthreads();
        if (active) {
            float r[RW][RW];
            #pragma unroll
            for (int rr = 0; rr < RW; rr++) {
                int rowbase = (2 * ty * STRIDE + rr) * PADW + 2 * tx * STRIDE;
                if (STRIDE == 1) {
                    float2 a = *(const float2*)&patch[rowbase];
                    float2 c = *(const float2*)&patch[rowbase + 2];
                    r[rr][0] = a.x; r[rr][1] = a.y; r[rr][2] = c.x; r[rr][3] = c.y;
                } else {
                    float4 a = *(const float4*)&patch[rowbase];
                    r[rr][0] = a.x; r[rr][1] = a.y; r[rr][2] = a.z; r[rr][3] = a.w;
                    r[rr][4] = patch[rowbase + 4];
                }
            }
            const float* wb = wgt + ((size_t)co0 * Cin + ci) * 9;
            #pragma unroll
            for (int i = 0; i < COPB; i++) {
                const float* wp = wb + (size_t)i * Cin * 9;
                #pragma unroll
                for (int ki = 0; ki < 3; ki++)
                    #pragma unroll
                    for (int kj = 0; kj < 3; kj++) {
                        float w = wp[ki * 3 + kj];
                        acc[i][0] = fmaf(r[ki][kj],                   w, acc[i][0]);
                        acc[i][1] = fmaf(r[ki][kj + STRIDE],          w, acc[i][1]);
                        acc[i][2] = fmaf(r[ki + STRIDE][kj],          w, acc[i][2]);
                        acc[i][3] = fmaf(r[ki + STRIDE][kj + STRIDE], w, acc[i][3]);
                    }
            }
        }
        __syncthreads();
    }
    if (active) {
        #pragma unroll
        for (int rr = 0; rr < 2; rr++) {
            #pragma unroll
            for (int cc = 0; cc < 2; cc++) {
                int oy = py + rr, ox = px + cc;
                if (oy < Ho && ox < Wo) {
                    #pragma unroll
                    for (int i = 0; i < COPB; i++) {
                        float v = acc[i][rr * 2 + cc];
                        if (do_relu) v = fmaxf(v, 0.f);
                        out[(((size_t)b * Cout + co0 + i) * Ho + oy) * Wo + ox] = v;
                    }
                }
            }
        }
    }
}

// ---------------------------------------------------------------------------
__global__ __launch_bounds__(256) void bn_stats_kernel(
    const float* __restrict__ x, float* __restrict__ stats,
    int B, int C, int HW)
{
    int c = blockIdx.x;
    long long cnt = (long long)B * HW;
    long long step = (long long)gridDim.y * blockDim.x;
    float s = 0.f, s2 = 0.f;
    for (long long t = (long long)blockIdx.y * blockDim.x + threadIdx.x; t < cnt; t += step) {
        int b  = (int)(t / HW);
        int sp = (int)(t % HW);
        float v = x[((size_t)b * C + c) * (size_t)HW + sp];
        s += v; s2 += v * v;
    }
    for (int off = 32; off; off >>= 1) {
        s  += __shfl_down(s, off);
        s2 += __shfl_down(s2, off);
    }
    __shared__ float ls[4], ls2[4];
    int wave = threadIdx.x >> 6, lane = threadIdx.x & 63;
    if (lane == 0) { ls[wave] = s; ls2[wave] = s2; }
    __syncthreads();
    if (threadIdx.x == 0) {
        float ts = 0.f, ts2 = 0.f;
        for (int i = 0; i < 4; i++) { ts += ls[i]; ts2 += ls2[i]; }
        atomicAdd(&stats[c], ts);
        atomicAdd(&stats[C + c], ts2);
    }
}

// ---------------------------------------------------------------------------
__global__ void zero_kernel(float* __restrict__ p, int n)
{
    int i = blockIdx.x * blockDim.x + threadIdx.x;
    if (i < n) p[i] = 0.f;
}

// ---------------------------------------------------------------------------
__global__ __launch_bounds__(256) void pool_kernel(
    const float* __restrict__ x, const float* __restrict__ stats,
    const float* __restrict__ g, const float* __restrict__ be,
    float inv_cnt, float* __restrict__ out, int C, int HW)
{
    int bc = blockIdx.x;
    int c  = bc % C;
    const float* xp = x + (size_t)bc * HW;
    float s = 0.f;
    for (int i = threadIdx.x; i < HW; i += blockDim.x) s += xp[i];
    for (int off = 32; off; off >>= 1) s += __shfl_down(s, off);
    __shared__ float ls[4];
    int wave = threadIdx.x >> 6, lane = threadIdx.x & 63;
    if (lane == 0) ls[wave] = s;
    __syncthreads();
    if (threadIdx.x == 0) {
        float t = 0.f;
        for (int i = 0; i < 4; i++) t += ls[i];
        float mean = t / (float)HW;
        float m  = stats[c] * inv_cnt;
        float vv = stats[C + c] * inv_cnt - m * m;
        float sc = g[c] / sqrtf(vv + BN_EPS);
        float sh = be[c] - m * sc;
        out[bc] = mean * sc + sh;
    }
}

// ---------------------------------------------------------------------------
__global__ __launch_bounds__(128) void fc_softmax_kernel(
    const float* __restrict__ pool, const float* __restrict__ wfc,
    const float* __restrict__ bfc, float* __restrict__ out)
{
    int b = blockIdx.x;
    __shared__ float row[128];
    __shared__ float logits[10];
    int tid = threadIdx.x;
    row[tid] = pool[b * 128 + tid];
    __syncthreads();
    if (tid < 10) {
        float s = bfc[tid];
        for (int k = 0; k < 128; k++) s = fmaf(row[k], wfc[tid * 128 + k], s);
        logits[tid] = s;
    }
    __syncthreads();
    if (tid < 10) {
        float mx = logits[0];
        for (int i = 1; i < 10; i++) mx = fmaxf(mx, logits[i]);
        float sum = 0.f;
        for (int i = 0; i < 10; i++) sum += expf(logits[i] - mx);
        out[b * 10 + tid] = expf(logits[tid] - mx) / sum;
    }
}

// ---------------------------------------------------------------------------
// Region ping-pong: two 102.8 MB regions R0/R1 alternate between
// {fp32 conv output} -> {tiled+linear fp16 planes} -> {packed u32 conv input}.
// Live-range audit per stage done r17; no overlap.
// ---------------------------------------------------------------------------
extern "C" void kernel_launch(void* const* d_in, const int* in_sizes, int n_in,
                              void* d_out, int out_size, void* d_ws, size_t ws_size,
                              hipStream_t stream)
{
    const float* x      = (const float*)d_in[0];
    const float* w11    = (const float*)d_in[1];
    const float* b11    = (const float*)d_in[2];
    const float* g11    = (const float*)d_in[3];
    const float* be11   = (const float*)d_in[4];
    const float* woff12 = (const float*)d_in[5];
    const float* w12    = (const float*)d_in[6];
    const float* b12    = (const float*)d_in[7];
    const float* g12    = (const float*)d_in[8];
    const float* be12   = (const float*)d_in[9];
    const float* woff21 = (const float*)d_in[10];
    const float* w21    = (const float*)d_in[11];
    const float* b21    = (const float*)d_in[12];
    const float* g21    = (const float*)d_in[13];
    const float* be21   = (const float*)d_in[14];
    const float* woff22 = (const float*)d_in[15];
    const float* w22    = (const float*)d_in[16];
    const float* b22    = (const float*)d_in[17];
    const float* g22    = (const float*)d_in[18];
    const float* be22   = (const float*)d_in[19];
    const float* wfc    = (const float*)d_in[20];
    const float* bfc    = (const float*)d_in[21];
    float* out = (float*)d_out;

    float* ws    = (float*)d_ws;
    const size_t SZ_B = 25690112;   // 64*32*112*112 = 64*128*56*56 elements

    // Region 0
    float*  R0f = ws;
    uint_t* R0u = (uint_t*)R0f;
    half_t* R0h = (half_t*)R0f;          // tiled fp16 plane
    half_t* R0l = R0h + SZ_B;            // linear fp16 plane
    float* stats = R0f + SZ_B;           // 512
    float* aff   = stats + 512;          // 512
    float* poolb = aff + 512;            // 8192
    // Region 1
    uint_t* R1u = (uint_t*)(poolb + 8192);
    float*  R1f = (float*)R1u;
    half_t* R1h = (half_t*)R1u;
    half_t* R1l = R1h + SZ_B;
    // Weights
    ushort_t* warena = (ushort_t*)(R1u + SZ_B);
    const size_t W12 = 9 * 64 * 32;
    const size_t W21 = 9 * 128 * 64;
    const size_t W22c = 9 * 128 * 128;
    const size_t W12o = 9 * 64 * 32;
    const size_t W21o = 9 * 128 * 64;
    ushort_t* wc12h = warena;          ushort_t* wc12l = wc12h + W12;
    ushort_t* wc21h = wc12l + W12;     ushort_t* wc21l = wc21h + W21;
    ushort_t* wc22h = wc21l + W21;     ushort_t* wc22l = wc22h + W22c;
    half_t* wpf12 = (half_t*)(wc22l + W22c);
    half_t* wpf21 = wpf12 + W12o;
    half_t* wpf22 = wpf21 + W21o;

    const int B = 64;

    // ---- weight prep ----
    prep_w_kernel<<<(9*64*32   + 255)/256, 256, 0, stream>>>(w12, wc12h, wc12l, 64, 32);
    prep_w_kernel<<<(9*128*64  + 255)/256, 256, 0, stream>>>(w21, wc21h, wc21l, 128, 64);
    prep_w_kernel<<<(9*128*128 + 255)/256, 256, 0, stream>>>(w22, wc22h, wc22l, 128, 128);
    prep_wf16_kernel<<<(9*64*32   + 255)/256, 256, 0, stream>>>(woff12, wpf12, 64, 32);
    prep_wf16_kernel<<<(9*128*64  + 255)/256, 256, 0, stream>>>(woff21, wpf21, 128, 64);
    prep_wf16_kernel<<<(9*256*128 + 255)/256, 256, 0, stream>>>(woff22, wpf22, 256, 128);

    // ---- Layer 1.1: conv(1->32, s1)+relu -> R0f; stats; finalize ----
    conv3x3_kernel<1><<<dim3(4, 4, B * (32 / 8)), 256, 0, stream>>>(
        x, w11, b11, R0f, B, 1, 112, 112, 32, 112, 112, 1);
    zero_kernel<<<2, 256, 0, stream>>>(stats, 512);
    bn_stats_kernel<<<dim3(32, 64), 256, 0, stream>>>(R0f, stats, B, 32, 12544);
    bn_finalize_kernel<<<1, 256, 0, stream>>>(stats, g11, be11, 1.f/(64.f*12544.f), aff, 32);

    // ---- deform12: pack BN(1.1) R0f -> R1 planes; deform -> R0 packed ----
    pack_af16_kernel<<<(B*4*12544 + 255)/256, 256, 0, stream>>>(
        R0f, aff, R1h, R1l, 32, 12544, B*4*12544);
    mfma_deform_g<112, 112, 32, 64, 2, 1>
        <<<dim3(64 * 49), 512, 0, stream>>>(R1h, R1l, wpf12, R0u);

    // ---- Layer 1.2 (MFMA s2, staged): conv(R0 packed) -> R1f ----
    mfma_conv_g<2, 112, 112, 32, 64, 2, 1>
        <<<dim3(64 * 13), 512, 0, stream>>>(R0u, wc12h, wc12l, b12, R1f);
    zero_kernel<<<2, 256, 0, stream>>>(stats, 512);
    bn_stats_kernel<<<dim3(64, 64), 256, 0, stream>>>(R1f, stats, B, 64, 3136);
    bn_finalize_kernel<<<1, 256, 0, stream>>>(stats, g12, be12, 1.f/(64.f*3136.f), aff, 64);

    // ---- deform21: pack BN(1.2) R1f -> R0 planes; deform -> R1 packed ----
    pack_af16_kernel<<<(B*8*3136 + 255)/256, 256, 0, stream>>>(
        R1f, aff, R0h, R0l, 64, 3136, B*8*3136);
    mfma_deform_g<56, 56, 64, 128, 4, 1>
        <<<dim3(64 * 13), 512, 0, stream>>>(R0h, R0l, wpf21, R1u);

    // ---- Layer 2.1 (MFMA s1, staged): conv(R1 packed) -> R0f ----
    mfma_conv_g<1, 56, 56, 64, 128, 2, 2>
        <<<dim3(64 * 26), 512, 0, stream>>>(R1u, wc21h, wc21l, b21, R0f);
    zero_kernel<<<2, 256, 0, stream>>>(stats, 512);
    bn_stats_kernel<<<dim3(128, 64), 256, 0, stream>>>(R0f, stats, B, 128, 3136);
    bn_finalize_kernel<<<1, 256, 0, stream>>>(stats, g21, be21, 1.f/(64.f*3136.f), aff, 128);

    // ---- deform22: pack BN(2.1) R0f -> R1 planes; deform -> R0 packed ----
    pack_af16_kernel<<<(B*16*3136 + 255)/256, 256, 0, stream>>>(
        R0f, aff, R1h, R1l, 128, 3136, B*16*3136);
    mfma_deform_g<56, 56, 128, 256, 4, 2>
        <<<dim3(64 * 26), 512, 0, stream>>>(R1h, R1l, wpf22, R0u);

    // ---- Layer 2.2 (MFMA s2, staged): conv(R0 packed) -> R1f ----
    mfma_conv_g<2, 56, 56, 128, 128, 2, 2>
        <<<dim3(64 * 8), 512, 0, stream>>>(R0u, wc22h, wc22l, b22, R1f);
    zero_kernel<<<2, 256, 0, stream>>>(stats, 512);
    bn_stats_kernel<<<dim3(128, 64), 256, 0, stream>>>(R1f, stats, B, 128, 784);

    // ---- Pool (BN(2.2) fused) + FC + softmax ----
    pool_kernel<<<B * 128, 256, 0, stream>>>(
        R1f, stats, g22, be22, 1.f/(64.f*784.f), poolb, 128, 784);
    fc_softmax_kernel<<<B, 128, 0, stream>>>(poolb, wfc, bfc, out);
}